// Round 1
// baseline (760.413 us; speedup 1.0000x reference)
//
#include <hip/hip_runtime.h>
#include <math.h>

// ---------------- reductions ----------------

__device__ __forceinline__ float wave_reduce_sum(float v) {
    #pragma unroll
    for (int o = 32; o > 0; o >>= 1) v += __shfl_down(v, o, 64);
    return v;
}

// Valid result only on threadIdx.x == 0. Safe to call repeatedly (leading
// __syncthreads guards the shared buffer against the previous call's readers).
__device__ float block_reduce_sum(float v) {
    __shared__ float s[8];
    __syncthreads();
    const int lane = threadIdx.x & 63;
    const int wid  = threadIdx.x >> 6;
    v = wave_reduce_sum(v);
    if (lane == 0) s[wid] = v;
    __syncthreads();
    float r = 0.f;
    if (wid == 0) {
        float x = (lane < (int)(blockDim.x >> 6)) ? s[lane] : 0.f;
        r = wave_reduce_sum(x);
    }
    return r;
}

// ---------------- kernels ----------------

// acc layout: [0]=focal_sum [1]=total_demand [2]=mask_cnt [3]=node_sq
//             [4]=coverage_sum [5]=tour_sum
__global__ void edge_kernel(const float* __restrict__ ep,
                            const float* __restrict__ ye,
                            const int*   __restrict__ src,
                            const int*   __restrict__ dst,
                            float* __restrict__ in_sums,
                            float* __restrict__ out_sums,
                            float* __restrict__ acc,
                            int E) {
    float local = 0.f;
    for (int i = blockIdx.x * blockDim.x + threadIdx.x; i < E;
         i += gridDim.x * blockDim.x) {
        const float x = ep[i];
        const float t = ye[i];
        const float p = 1.f / (1.f + expf(-x));
        atomicAdd(&out_sums[src[i]], p);
        atomicAdd(&in_sums[dst[i]], p);
        // focal loss term
        const float bce = fmaxf(x, 0.f) - x * t + log1pf(expf(-fabsf(x)));
        const float p_t = p * t + (1.f - p) * (1.f - t);
        const float a_t = 0.25f * t + 0.75f * (1.f - t);
        const float om  = 1.f - p_t;
        local += a_t * om * om * bce;
    }
    const float bs = block_reduce_sum(local);
    if (threadIdx.x == 0) atomicAdd(&acc[0], bs);
}

__global__ void node_kernel(const float* __restrict__ npred,
                            const float* __restrict__ yn,
                            const float* __restrict__ x,
                            float* __restrict__ acc,
                            int N) {
    const int i = blockIdx.x * blockDim.x + threadIdx.x;
    float dem = 0.f, cnt = 0.f, sq = 0.f;
    if (i < N) {
        if (i >= 1) dem = x[i * 4 + 2];
        const float y = yn[i];
        if (y >= 0.f) {
            cnt = 1.f;
            const float d = npred[i] - y;
            sq = d * d;
        }
    }
    float b;
    b = block_reduce_sum(dem); if (threadIdx.x == 0) atomicAdd(&acc[1], b);
    b = block_reduce_sum(cnt); if (threadIdx.x == 0) atomicAdd(&acc[2], b);
    b = block_reduce_sum(sq);  if (threadIdx.x == 0) atomicAdd(&acc[3], b);
}

__global__ void cov_kernel(const float* __restrict__ in_sums,
                           const float* __restrict__ out_sums,
                           float* __restrict__ acc,
                           int N) {
    const int i = blockIdx.x * blockDim.x + threadIdx.x;
    float cov = 0.f, tour = 0.f;
    if (i < N) {
        const float a = in_sums[i];
        const float b = out_sums[i];
        const float d = a - b;
        tour = d * d;
        if (i >= 1) cov = (a - 1.f) * (a - 1.f) + (b - 1.f) * (b - 1.f);
    }
    float r;
    r = block_reduce_sum(cov);  if (threadIdx.x == 0) atomicAdd(&acc[4], r);
    r = block_reduce_sum(tour); if (threadIdx.x == 0) atomicAdd(&acc[5], r);
}

__global__ void final_kernel(const float* __restrict__ in_sums,
                             const float* __restrict__ out_sums,
                             const float* __restrict__ acc,
                             const float* __restrict__ capacity,
                             float* __restrict__ out,
                             int N, int E) {
    const float coverage = acc[4] / (2.0f * (float)(N - 1));
    const float tour     = acc[5] / (float)N;
    const float in0  = in_sums[0];
    const float out0 = out_sums[0];
    const float depot = (in0 - out0) * (in0 - out0);
    const float cap = capacity[0];
    const float expected = ceilf(acc[1] / cap);
    const float cap_t = (out0 - expected) * (out0 - expected);
    const float sim = acc[0] / (float)E;
    const float node_loss = acc[3] / fmaxf(acc[2], 1.f);
    out[0] = coverage * 5.f + tour * 3.f + depot * 2.f + cap_t * 1.5f +
             sim * 0.3f + node_loss * 0.1f;
}

// ---------------- launch ----------------

extern "C" void kernel_launch(void* const* d_in, const int* in_sizes, int n_in,
                              void* d_out, int out_size, void* d_ws, size_t ws_size,
                              hipStream_t stream) {
    const float* ep       = (const float*)d_in[0];   // edge_predictions [E]
    const float* npred    = (const float*)d_in[1];   // node_predictions [N]
    const float* x        = (const float*)d_in[2];   // x [N,4]
    const float* capacity = (const float*)d_in[3];   // capacity [1]
    const float* ye       = (const float*)d_in[4];   // y_edges [E]
    const float* yn       = (const float*)d_in[5];   // y_nodes [N]
    const int*   ei       = (const int*)d_in[6];     // edge_index [2,E] (int32)

    const int E = in_sizes[0];
    const int N = in_sizes[1];
    const int* src = ei;
    const int* dst = ei + E;

    float* in_sums  = (float*)d_ws;
    float* out_sums = in_sums + N;
    float* acc      = out_sums + N;

    hipMemsetAsync(d_ws, 0, (size_t)(2 * N + 8) * sizeof(float), stream);

    const int tb = 256;
    const int edge_blocks = 4096;
    edge_kernel<<<edge_blocks, tb, 0, stream>>>(ep, ye, src, dst, in_sums,
                                                out_sums, acc, E);
    node_kernel<<<(N + tb - 1) / tb, tb, 0, stream>>>(npred, yn, x, acc, N);
    cov_kernel<<<(N + tb - 1) / tb, tb, 0, stream>>>(in_sums, out_sums, acc, N);
    final_kernel<<<1, 1, 0, stream>>>(in_sums, out_sums, acc, capacity,
                                      (float*)d_out, N, E);
}